// Round 8
// baseline (313.589 us; speedup 1.0000x reference)
//
#include <hip/hip_runtime.h>

#define N_NODES 20000
#define N_EDGES 320000
#define IN_CH 256
#define HID_CH 512

typedef unsigned short u16;
typedef __attribute__((ext_vector_type(4))) float f32x4;
typedef __attribute__((ext_vector_type(8))) short bf16x8;
typedef __attribute__((ext_vector_type(4))) u16 u16x4;

__device__ __forceinline__ float bf2f(u16 h) { return __uint_as_float((unsigned)h << 16); }
__device__ __forceinline__ u16 f2bf(float f) {  // round-to-nearest-even
    unsigned u = __float_as_uint(f);
    return (u16)((u + 0x7fffu + ((u >> 16) & 1u)) >> 16);
}

// ---------------------------------------------------------------- CSR build
__global__ void count_deg_kernel(const int* __restrict__ dst, int* __restrict__ deg, int E) {
    int i = blockIdx.x * blockDim.x + threadIdx.x;
    if (i < E) atomicAdd(&deg[dst[i]], 1);
}

// single-block scan: row_ptr (exclusive) + dinv = rsqrt(deg+1)
__global__ __launch_bounds__(256) void scan_kernel(const int* __restrict__ deg,
                                                   int* __restrict__ row_ptr,
                                                   float* __restrict__ dinv, int N) {
    __shared__ int sums[256];
    int t = threadIdx.x;
    const int CH = (N + 255) / 256;
    int base = t * CH;
    int s = 0;
    for (int i = 0; i < CH; ++i) {
        int idx = base + i;
        if (idx < N) {
            int d = deg[idx];
            dinv[idx] = rsqrtf((float)d + 1.0f);
            s += d;
        }
    }
    sums[t] = s;
    __syncthreads();
    for (int off = 1; off < 256; off <<= 1) {
        int v = (t >= off) ? sums[t - off] : 0;
        __syncthreads();
        if (t >= off) sums[t] += v;
        __syncthreads();
    }
    int run = (t == 0) ? 0 : sums[t - 1];
    for (int i = 0; i < CH; ++i) {
        int idx = base + i;
        if (idx <= N) row_ptr[idx] = run;
        if (idx < N) run += deg[idx];
    }
}

// bucket-scatter: epair[pos] = {src, bits(dinv[src])}
__global__ void scatter_edges_kernel(const int* __restrict__ src, const int* __restrict__ dst,
                                     const int* __restrict__ row_ptr, int* __restrict__ cursor,
                                     const float* __restrict__ dinv, int2* __restrict__ epair,
                                     int E) {
    int e = blockIdx.x * blockDim.x + threadIdx.x;
    if (e >= E) return;
    int d = dst[e];
    int s = src[e];
    int pos = row_ptr[d] + atomicAdd(&cursor[d], 1);
    epair[pos] = make_int2(s, __float_as_int(dinv[s]));
}

// ---------------------------------------------------------------- conversions
__global__ void f32_to_bf16_kernel(const float* __restrict__ in, u16* __restrict__ out, int n4) {
    int i = blockIdx.x * blockDim.x + threadIdx.x;
    if (i >= n4) return;
    float4 v = ((const float4*)in)[i];
    u16x4 o = {f2bf(v.x), f2bf(v.y), f2bf(v.z), f2bf(v.w)};
    ((u16x4*)out)[i] = o;
}

// both weights: W [K][N] f32 -> Wt hi/lo [N][K] bf16 (LDS-tiled transpose + split)
__global__ __launch_bounds__(256) void convert_w_kernel(const float* __restrict__ W1,
                                                        u16* __restrict__ hi1, u16* __restrict__ lo1,
                                                        const float* __restrict__ W2,
                                                        u16* __restrict__ hi2, u16* __restrict__ lo2) {
    __shared__ float t[64][65];
    int b = blockIdx.x;
    const float* W;
    u16 *hi, *lo;
    int K;
    if (b < 32) { W = W1; hi = hi1; lo = lo1; K = IN_CH; }
    else        { b -= 32; W = W2; hi = hi2; lo = lo2; K = HID_CH; }
    const int N = HID_CH;
    int k0 = (b >> 3) * 64, n0 = (b & 7) * 64;
    int c = threadIdx.x & 63, r4 = threadIdx.x >> 6;
#pragma unroll
    for (int i = 0; i < 16; ++i) {
        int r = i * 4 + r4;
        t[r][c] = W[(size_t)(k0 + r) * N + n0 + c];
    }
    __syncthreads();
#pragma unroll
    for (int i = 0; i < 16; ++i) {
        int n = i * 4 + r4;
        float f = t[c][n];
        u16 hb = f2bf(f);
        size_t o = (size_t)(n0 + n) * K + k0 + c;
        hi[o] = hb;
        lo[o] = f2bf(f - bf2f(hb));
    }
}

// ---------------------------------------------------------------- XCD-sliced gather-aggregate
// z[n] = h[n]*dinv[n]^2 + sum_e h[src]*norm_e*dinv[n]
// Channel slice s (64 ch = 2.56 MB table slice) pinned to XCD(s) via bid%8 -> L2-resident.
template <int C, int SLICES>
__global__ void gather_agg_kernel(const u16* __restrict__ h, const int2* __restrict__ epair,
                                  const int* __restrict__ row_ptr, const float* __restrict__ dinv,
                                  u16* __restrict__ z_hi, u16* __restrict__ z_lo, int N) {
    constexpr int SC = C / SLICES;  // 64 channels per slice = 1 per lane
    static_assert(SC == 64, "one channel per lane");
    int bid = blockIdx.x;
    int nb, s;
    if (SLICES == 8) {          // slice = XCD
        nb = bid >> 3;
        s = bid & 7;
    } else {                    // SLICES == 4: slice on XCD pair {2s,2s+1}
        nb = (bid >> 3) * 2 + (bid & 1);
        s = (bid & 7) >> 1;
    }
    int wid = threadIdx.x >> 6;
    int lane = threadIdx.x & 63;
    int n = nb * 4 + wid;
    if (n >= N) return;
    float dn = dinv[n];
    const u16* hcol = h + s * SC + lane;  // column (s*64+lane), row stride C
    float acc = bf2f(hcol[(size_t)n * C]) * dn * dn;
    int e0 = row_ptr[n], e1 = row_ptr[n + 1];
    int e = e0;
    for (; e + 8 <= e1; e += 8) {
        int2 p0 = epair[e + 0], p1 = epair[e + 1], p2 = epair[e + 2], p3 = epair[e + 3];
        int2 p4 = epair[e + 4], p5 = epair[e + 5], p6 = epair[e + 6], p7 = epair[e + 7];
        u16 v0 = hcol[(size_t)p0.x * C], v1 = hcol[(size_t)p1.x * C];
        u16 v2 = hcol[(size_t)p2.x * C], v3 = hcol[(size_t)p3.x * C];
        u16 v4 = hcol[(size_t)p4.x * C], v5 = hcol[(size_t)p5.x * C];
        u16 v6 = hcol[(size_t)p6.x * C], v7 = hcol[(size_t)p7.x * C];
        acc = fmaf(bf2f(v0), __int_as_float(p0.y) * dn, acc);
        acc = fmaf(bf2f(v1), __int_as_float(p1.y) * dn, acc);
        acc = fmaf(bf2f(v2), __int_as_float(p2.y) * dn, acc);
        acc = fmaf(bf2f(v3), __int_as_float(p3.y) * dn, acc);
        acc = fmaf(bf2f(v4), __int_as_float(p4.y) * dn, acc);
        acc = fmaf(bf2f(v5), __int_as_float(p5.y) * dn, acc);
        acc = fmaf(bf2f(v6), __int_as_float(p6.y) * dn, acc);
        acc = fmaf(bf2f(v7), __int_as_float(p7.y) * dn, acc);
    }
    for (; e < e1; ++e) {
        int2 p = epair[e];
        acc = fmaf(bf2f(hcol[(size_t)p.x * C]), __int_as_float(p.y) * dn, acc);
    }
    u16 hb = f2bf(acc);
    size_t o = (size_t)n * C + s * SC + lane;
    z_hi[o] = hb;
    z_lo[o] = f2bf(acc - bf2f(hb));
}

// ---------------------------------------------------------------- split-bf16 MFMA GEMM
// C = (Ah+Al)@(Bh+Bl) + bias; B transposed [N][K]. BM=192, BN=128, BK=32; 12 waves (3x4
// of 64x32); dbuf LDS 2x40KB = 80KB -> 2 blocks/CU = 160KB; grid = ceil(M/192)*4 = 420
// blocks <= 512 slots -> ONE dispatch round (kills the 1.5-block-time quantization tail).
// Counted-vmcnt pipeline (T4); LDS swizzle byte^=((row>>1)&3)<<4 (conflict-free, R7-verified).
template <int K, bool RELU, bool OUT_BF16>
__global__ __launch_bounds__(768, 6) void gemm_mfma_kernel(
        const u16* __restrict__ Ah, const u16* __restrict__ Al, const u16* __restrict__ Bh,
        const u16* __restrict__ Bl, const float* __restrict__ bias, void* __restrict__ Cout,
        int M, int N) {
    // flat buffer layout (bytes): Ah@0 (12K), Al@12288, Bh@24576 (8K), Bl@32768 -> 40KB/buf
    __shared__ u16 lds[2][20480];
    const int tid = threadIdx.x;
    const int lane = tid & 63;
    const int wid = tid >> 6;

    // bijective XCD-chunked swizzle (m204)
    const int nmt = (M + 191) / 192;
    const int total = nmt * 4;
    int bid = blockIdx.x;
    int q = total >> 3, r = total & 7;
    int xcd = bid & 7, pp = bid >> 3;
    int lin = (xcd < r) ? (xcd * (q + 1) + pp) : (r * (q + 1) + (xcd - r) * q + pp);
    const int bm = (lin >> 2) * 192;
    const int bn = (lin & 3) * 128;

    const int wm = (wid >> 2) * 64;  // 3 wave-rows
    const int wn = (wid & 3) * 32;   // 4 wave-cols

    f32x4 acc[4][2];
#pragma unroll
    for (int i = 0; i < 4; ++i)
#pragma unroll
        for (int j = 0; j < 2; ++j) acc[i][j] = (f32x4){0.f, 0.f, 0.f, 0.f};

    // staging: A planes 768 chunks (1/thread), B planes 512 chunks (waves 8-11 issue
    // benign duplicates of waves 0-3's chunks -> uniform 4 loads/thread -> uniform vmcnt)
    const int arow = tid >> 2;
    const int acb = (tid & 3) << 4;
    const int ascb = acb ^ (((arow >> 1) & 3) << 4);
    const int grA = min(bm + arow, M - 1);
    const char* srcAh = (const char*)(Ah + (size_t)grA * K) + ascb;
    const char* srcAl = (const char*)(Al + (size_t)grA * K) + ascb;
    const int bwid = wid & 7;
    const int bchunk = bwid * 64 + lane;  // 0..511
    const int brow = bchunk >> 2;         // 0..127
    const int bcb = (bchunk & 3) << 4;
    const int bscb = bcb ^ (((brow >> 1) & 3) << 4);
    const int grB = bn + brow;
    const char* srcBh = (const char*)(Bh + (size_t)grB * K) + bscb;
    const char* srcBl = (const char*)(Bl + (size_t)grB * K) + bscb;
    const int adst = wid << 10;   // wave-uniform A dest base
    const int bdst = bwid << 10;  // wave-uniform B dest base

#define STAGE(buf, k0)                                                                    \
    do {                                                                                  \
        size_t kb2 = (size_t)(k0) * 2;                                                    \
        char* L0 = (char*)&lds[buf][0];                                                   \
        __builtin_amdgcn_global_load_lds(                                                 \
            (const __attribute__((address_space(1))) void*)(srcAh + kb2),                 \
            (__attribute__((address_space(3))) void*)(L0 + adst), 16, 0, 0);              \
        __builtin_amdgcn_global_load_lds(                                                 \
            (const __attribute__((address_space(1))) void*)(srcAl + kb2),                 \
            (__attribute__((address_space(3))) void*)(L0 + 12288 + adst), 16, 0, 0);      \
        __builtin_amdgcn_global_load_lds(                                                 \
            (const __attribute__((address_space(1))) void*)(srcBh + kb2),                 \
            (__attribute__((address_space(3))) void*)(L0 + 24576 + bdst), 16, 0, 0);      \
        __builtin_amdgcn_global_load_lds(                                                 \
            (const __attribute__((address_space(1))) void*)(srcBl + kb2),                 \
            (__attribute__((address_space(3))) void*)(L0 + 32768 + bdst), 16, 0, 0);      \
    } while (0)

    STAGE(0, 0);

    const int NT = K / 32;
    const int kb = (lane >> 4) << 4;  // fragment k byte-offset within 64B row
#pragma unroll
    for (int t = 0; t < NT; ++t) {
        int cur = t & 1;
        if (t + 1 < NT) {
            STAGE(cur ^ 1, (t + 1) * 32);
            asm volatile("s_waitcnt vmcnt(4)" ::: "memory");  // wait prev tile only
        } else {
            asm volatile("s_waitcnt vmcnt(0)" ::: "memory");
        }
        __builtin_amdgcn_s_barrier();
        asm volatile("" ::: "memory");

        const char* L = (const char*)&lds[cur][0];
        bf16x8 a_h[4], a_l[4], b_h[2], b_l[2];
#pragma unroll
        for (int i = 0; i < 4; ++i) {
            int ra = wm + i * 16 + (lane & 15);
            int off = ra * 64 + (kb ^ (((ra >> 1) & 3) << 4));
            a_h[i] = *(const bf16x8*)(L + off);
            a_l[i] = *(const bf16x8*)(L + 12288 + off);
        }
#pragma unroll
        for (int j = 0; j < 2; ++j) {
            int rb = wn + j * 16 + (lane & 15);
            int off = rb * 64 + (kb ^ (((rb >> 1) & 3) << 4));
            b_h[j] = *(const bf16x8*)(L + 24576 + off);
            b_l[j] = *(const bf16x8*)(L + 32768 + off);
        }
#pragma unroll
        for (int i = 0; i < 4; ++i)
#pragma unroll
            for (int j = 0; j < 2; ++j) {
                acc[i][j] = __builtin_amdgcn_mfma_f32_16x16x32_bf16(a_h[i], b_h[j], acc[i][j], 0, 0, 0);
                acc[i][j] = __builtin_amdgcn_mfma_f32_16x16x32_bf16(a_l[i], b_h[j], acc[i][j], 0, 0, 0);
                acc[i][j] = __builtin_amdgcn_mfma_f32_16x16x32_bf16(a_h[i], b_l[j], acc[i][j], 0, 0, 0);
            }
        asm volatile("" ::: "memory");
        __builtin_amdgcn_s_barrier();
    }
#undef STAGE

    // epilogue: C/D layout col=lane&15, row=(lane>>4)*4+t (m89/m91 verified)
#pragma unroll
    for (int j = 0; j < 2; ++j) {
        int gc = bn + wn + j * 16 + (lane & 15);
        float bv = bias[gc];
#pragma unroll
        for (int i = 0; i < 4; ++i) {
#pragma unroll
            for (int t = 0; t < 4; ++t) {
                int gr = bm + wm + i * 16 + ((lane >> 4) << 2) + t;
                if (gr < M) {
                    float v = acc[i][j][t] + bv;
                    if (RELU) v = fmaxf(v, 0.f);
                    if (OUT_BF16)
                        ((u16*)Cout)[(size_t)gr * N + gc] = f2bf(v);
                    else
                        ((float*)Cout)[(size_t)gr * N + gc] = v;
                }
            }
        }
    }
}

// ---------------------------------------------------------------- launch
extern "C" void kernel_launch(void* const* d_in, const int* in_sizes, int n_in,
                              void* d_out, int out_size, void* d_ws, size_t ws_size,
                              hipStream_t stream) {
    const float* x  = (const float*)d_in[0];
    const int*   ei = (const int*)d_in[1];
    const float* W1 = (const float*)d_in[2];
    const float* b1 = (const float*)d_in[3];
    const float* W2 = (const float*)d_in[4];
    const float* b2 = (const float*)d_in[5];
    const int* src = ei;
    const int* dst = ei + N_EDGES;

    char* ws = (char*)d_ws;
    size_t off = 0;
    auto alloc = [&](size_t bytes) {
        void* p = ws + off;
        off = (off + bytes + 255) & ~(size_t)255;
        return p;
    };
    int*   deg     = (int*)alloc(N_NODES * 4);  // reused as cursor
    int*   row_ptr = (int*)alloc((N_NODES + 1) * 4);
    float* dinv    = (float*)alloc(N_NODES * 4);
    int2*  epair   = (int2*)alloc((size_t)N_EDGES * 8);
    u16*   wt1_hi  = (u16*)alloc((size_t)IN_CH * HID_CH * 2);
    u16*   wt1_lo  = (u16*)alloc((size_t)IN_CH * HID_CH * 2);
    u16*   wt2_hi  = (u16*)alloc((size_t)HID_CH * HID_CH * 2);
    u16*   wt2_lo  = (u16*)alloc((size_t)HID_CH * HID_CH * 2);
    // overlay region: {xb, z1_hi, z1_lo} then {z2_hi, z2_lo}
    char*  R       = (char*)alloc((size_t)N_NODES * HID_CH * 2 * 2);  // 40.96 MB
    u16* xb    = (u16*)R;                                       // [N, 256]
    u16* z1_hi = (u16*)(R + (size_t)N_NODES * IN_CH * 2);       // [N, 256]
    u16* z1_lo = (u16*)(R + (size_t)N_NODES * IN_CH * 4);       // [N, 256]
    u16* z2_hi = (u16*)R;                                       // [N, 512] (over dead xb+z1_hi)
    u16* z2_lo = (u16*)(R + (size_t)N_NODES * HID_CH * 2);      // [N, 512] (over dead z1_lo)
    u16* h1    = (u16*)d_out;  // bf16 h1 scratch in d_out (dead before final GEMM writes)

    // CSR + dinv + epair
    hipMemsetAsync(deg, 0, N_NODES * 4, stream);
    count_deg_kernel<<<(N_EDGES + 255) / 256, 256, 0, stream>>>(dst, deg, N_EDGES);
    scan_kernel<<<1, 256, 0, stream>>>(deg, row_ptr, dinv, N_NODES);
    hipMemsetAsync(deg, 0, N_NODES * 4, stream);  // deg -> cursor
    scatter_edges_kernel<<<(N_EDGES + 255) / 256, 256, 0, stream>>>(src, dst, row_ptr, deg, dinv,
                                                                    epair, N_EDGES);

    // conversions
    f32_to_bf16_kernel<<<(N_NODES * IN_CH / 4 + 255) / 256, 256, 0, stream>>>(
        x, xb, N_NODES * IN_CH / 4);
    convert_w_kernel<<<96, 256, 0, stream>>>(W1, wt1_hi, wt1_lo, W2, wt2_hi, wt2_lo);

    const int NMT = (N_NODES + 191) / 192;  // 105
    // layer 1: z1 = P @ xb (4 slices on XCD pairs); h1 = relu(z1 @ W1 + b1) (bf16 out)
    gather_agg_kernel<IN_CH, 4><<<(N_NODES / 4 / 2) * 8, 256, 0, stream>>>(
        xb, epair, row_ptr, dinv, z1_hi, z1_lo, N_NODES);
    gemm_mfma_kernel<IN_CH, true, true><<<NMT * 4, 768, 0, stream>>>(
        z1_hi, z1_lo, wt1_hi, wt1_lo, b1, h1, N_NODES, HID_CH);

    // layer 2: z2 = P @ h1 (8 slices, one per XCD); out = z2 @ W2 + b2 (fp32 out)
    gather_agg_kernel<HID_CH, 8><<<(N_NODES / 4) * 8, 256, 0, stream>>>(
        h1, epair, row_ptr, dinv, z2_hi, z2_lo, N_NODES);
    gemm_mfma_kernel<HID_CH, false, false><<<NMT * 4, 768, 0, stream>>>(
        z2_hi, z2_lo, wt2_hi, wt2_lo, b2, (float*)d_out, N_NODES, HID_CH);
}

// Round 9
// 278.482 us; speedup vs baseline: 1.1261x; 1.1261x over previous
//
#include <hip/hip_runtime.h>

#define N_NODES 20000
#define N_EDGES 320000
#define IN_CH 256
#define HID_CH 512

typedef unsigned short u16;
typedef __attribute__((ext_vector_type(16))) float f32x16;
typedef __attribute__((ext_vector_type(8))) short bf16x8;
typedef __attribute__((ext_vector_type(4))) u16 u16x4;

__device__ __forceinline__ float bf2f(u16 h) { return __uint_as_float((unsigned)h << 16); }
__device__ __forceinline__ u16 f2bf(float f) {  // round-to-nearest-even
    unsigned u = __float_as_uint(f);
    return (u16)((u + 0x7fffu + ((u >> 16) & 1u)) >> 16);
}

// ---------------------------------------------------------------- CSR build
__global__ void count_deg_kernel(const int* __restrict__ dst, int* __restrict__ deg, int E) {
    int i = blockIdx.x * blockDim.x + threadIdx.x;
    if (i < E) atomicAdd(&deg[dst[i]], 1);
}

// single-block scan: row_ptr (exclusive) + dinv = rsqrt(deg+1)
__global__ __launch_bounds__(256) void scan_kernel(const int* __restrict__ deg,
                                                   int* __restrict__ row_ptr,
                                                   float* __restrict__ dinv, int N) {
    __shared__ int sums[256];
    int t = threadIdx.x;
    const int CH = (N + 255) / 256;
    int base = t * CH;
    int s = 0;
    for (int i = 0; i < CH; ++i) {
        int idx = base + i;
        if (idx < N) {
            int d = deg[idx];
            dinv[idx] = rsqrtf((float)d + 1.0f);
            s += d;
        }
    }
    sums[t] = s;
    __syncthreads();
    for (int off = 1; off < 256; off <<= 1) {
        int v = (t >= off) ? sums[t - off] : 0;
        __syncthreads();
        if (t >= off) sums[t] += v;
        __syncthreads();
    }
    int run = (t == 0) ? 0 : sums[t - 1];
    for (int i = 0; i < CH; ++i) {
        int idx = base + i;
        if (idx <= N) row_ptr[idx] = run;
        if (idx < N) run += deg[idx];
    }
}

// bucket-scatter: epair[pos] = {src, bits(dinv[src])}
__global__ void scatter_edges_kernel(const int* __restrict__ src, const int* __restrict__ dst,
                                     const int* __restrict__ row_ptr, int* __restrict__ cursor,
                                     const float* __restrict__ dinv, int2* __restrict__ epair,
                                     int E) {
    int e = blockIdx.x * blockDim.x + threadIdx.x;
    if (e >= E) return;
    int d = dst[e];
    int s = src[e];
    int pos = row_ptr[d] + atomicAdd(&cursor[d], 1);
    epair[pos] = make_int2(s, __float_as_int(dinv[s]));
}

// ---------------------------------------------------------------- conversions
__global__ void f32_to_bf16_kernel(const float* __restrict__ in, u16* __restrict__ out, int n4) {
    int i = blockIdx.x * blockDim.x + threadIdx.x;
    if (i >= n4) return;
    float4 v = ((const float4*)in)[i];
    u16x4 o = {f2bf(v.x), f2bf(v.y), f2bf(v.z), f2bf(v.w)};
    ((u16x4*)out)[i] = o;
}

// both weights: W [K][N] f32 -> Wt hi/lo [N][K] bf16 (LDS-tiled transpose + split)
__global__ __launch_bounds__(256) void convert_w_kernel(const float* __restrict__ W1,
                                                        u16* __restrict__ hi1, u16* __restrict__ lo1,
                                                        const float* __restrict__ W2,
                                                        u16* __restrict__ hi2, u16* __restrict__ lo2) {
    __shared__ float t[64][65];
    int b = blockIdx.x;
    const float* W;
    u16 *hi, *lo;
    int K;
    if (b < 32) { W = W1; hi = hi1; lo = lo1; K = IN_CH; }
    else        { b -= 32; W = W2; hi = hi2; lo = lo2; K = HID_CH; }
    const int N = HID_CH;
    int k0 = (b >> 3) * 64, n0 = (b & 7) * 64;
    int c = threadIdx.x & 63, r4 = threadIdx.x >> 6;
#pragma unroll
    for (int i = 0; i < 16; ++i) {
        int r = i * 4 + r4;
        t[r][c] = W[(size_t)(k0 + r) * N + n0 + c];
    }
    __syncthreads();
#pragma unroll
    for (int i = 0; i < 16; ++i) {
        int n = i * 4 + r4;
        float f = t[c][n];
        u16 hb = f2bf(f);
        size_t o = (size_t)(n0 + n) * K + k0 + c;
        hi[o] = hb;
        lo[o] = f2bf(f - bf2f(hb));
    }
}

// ---------------------------------------------------------------- gather-aggregate (R7 form + epair)
// z[n] = h[n]*dinv[n]^2 + sum_e h[src]*norm_e*dinv[n];  8-edge batched, full-row vector loads
template <int C>
__global__ void gather_agg_kernel(const u16* __restrict__ h, const int2* __restrict__ epair,
                                  const int* __restrict__ row_ptr, const float* __restrict__ dinv,
                                  u16* __restrict__ z_hi, u16* __restrict__ z_lo, int N) {
    constexpr int NV = C / 64;  // u16 per lane per row (4 or 8)
    typedef u16 vec_t __attribute__((ext_vector_type(NV)));
    int wave = (int)((blockIdx.x * blockDim.x + threadIdx.x) >> 6);
    int lane = threadIdx.x & 63;
    if (wave >= N) return;
    int n = wave;
    float dn = dinv[n];
    float self = dn * dn;
    const vec_t* hp = (const vec_t*)h;  // row r at vector index r*64 + lane
    float acc[NV];
    {
        vec_t v = hp[(size_t)n * 64 + lane];
#pragma unroll
        for (int j = 0; j < NV; ++j) acc[j] = bf2f(v[j]) * self;
    }
    int e0 = row_ptr[n], e1 = row_ptr[n + 1];
    int e = e0;
    for (; e + 8 <= e1; e += 8) {
        int2 p[8];
        vec_t w[8];
#pragma unroll
        for (int b = 0; b < 8; ++b) p[b] = epair[e + b];
#pragma unroll
        for (int b = 0; b < 8; ++b) w[b] = hp[(size_t)p[b].x * 64 + lane];
#pragma unroll
        for (int b = 0; b < 8; ++b) {
            float nr = __int_as_float(p[b].y) * dn;
#pragma unroll
            for (int j = 0; j < NV; ++j) acc[j] = fmaf(bf2f(w[b][j]), nr, acc[j]);
        }
    }
    for (; e < e1; ++e) {
        int2 p = epair[e];
        float nr = __int_as_float(p.y) * dn;
        vec_t w = hp[(size_t)p.x * 64 + lane];
#pragma unroll
        for (int j = 0; j < NV; ++j) acc[j] = fmaf(bf2f(w[j]), nr, acc[j]);
    }
    vec_t vh, vl;
#pragma unroll
    for (int j = 0; j < NV; ++j) {
        u16 hb = f2bf(acc[j]);
        vh[j] = hb;
        vl[j] = f2bf(acc[j] - bf2f(hb));
    }
    ((vec_t*)z_hi)[(size_t)n * 64 + lane] = vh;
    ((vec_t*)z_lo)[(size_t)n * 64 + lane] = vl;
}

// ---------------------------------------------------------------- split-bf16 MFMA GEMM (32x32x16)
// C = (Ah+Al)@(Bh+Bl) + bias; B transposed [N][K]. BM=192, BN=128, BK=32; 6 waves
// (3x2 of 64x64 wave tiles, 2x2 sub-tiles of 32x32); dbuf LDS 2x40KB = 80KB -> 2 blocks/CU.
// 32x32x16 MFMA: 2x the MACs per LDS byte vs 16x16x32 (the R7 kernel was LDS-read-bound:
// 96KB/K32 ~ 1130cy vs 230cy MFMA -> MfmaUtil 22%; now ~64KB vs ~810cy -> ~50%).
// Counted-vmcnt (T4) with uniform 6 loads/thread; grid 420 <= 512 -> one dispatch round.
template <int K, bool RELU, bool OUT_BF16>
__global__ __launch_bounds__(384, 3) void gemm_mfma_kernel(
        const u16* __restrict__ Ah, const u16* __restrict__ Al, const u16* __restrict__ Bh,
        const u16* __restrict__ Bl, const float* __restrict__ bias, void* __restrict__ Cout,
        int M, int N) {
    // buffer layout (bytes): Ah@0 (12K), Al@12288, Bh@24576 (8K), Bl@32768 -> 40KB/buf
    __shared__ u16 lds[2][20480];
    const int tid = threadIdx.x;
    const int lane = tid & 63;
    const int wid = tid >> 6;  // 0..5

    // bijective XCD-chunked swizzle (m204)
    const int nmt = (M + 191) / 192;
    const int total = nmt * 4;
    int bid = blockIdx.x;
    int q = total >> 3, r = total & 7;
    int xcd = bid & 7, pp = bid >> 3;
    int lin = (xcd < r) ? (xcd * (q + 1) + pp) : (r * (q + 1) + (xcd - r) * q + pp);
    const int bm = (lin >> 2) * 192;
    const int bn = (lin & 3) * 128;

    const int wm = (wid >> 1) * 64;  // 3 wave-rows
    const int wn = (wid & 1) * 64;   // 2 wave-cols

    f32x16 acc[2][2];
#pragma unroll
    for (int i = 0; i < 2; ++i)
#pragma unroll
        for (int j = 0; j < 2; ++j) acc[i][j] = (f32x16)(0.f);

    // ---- staging geometry (16B chunks, 4 per 64B row; swizzle slot ^= (row>>1)&3)
    // A: 768 chunks/plane; thread stages chunk tid and 384+tid in each plane.
    const int ar0 = tid >> 2;                     // rows 0..95
    const int aslot = (tid & 3);
    const int ascb = (aslot ^ ((ar0 >> 1) & 3)) << 4;  // row+96 has same swizzle (96%8==0 in pairs)
    const int grA0 = min(bm + ar0, M - 1);
    const int grA1 = min(bm + ar0 + 96, M - 1);
    const char* sA0h = (const char*)(Ah + (size_t)grA0 * K) + ascb;
    const char* sA1h = (const char*)(Ah + (size_t)grA1 * K) + ascb;
    const char* sA0l = (const char*)(Al + (size_t)grA0 * K) + ascb;
    const char* sA1l = (const char*)(Al + (size_t)grA1 * K) + ascb;
    // B: 512 chunks/plane; waves 0-3 cover them (2/thread); waves 4-5 duplicate waves 0-1.
    const int bw = wid & 3;
    const int br0 = bw * 32 + (lane >> 2);        // j=0 row; j=1 row = +16
    const int bscb = ((lane & 3) ^ ((lane >> 3) & 3)) << 4;  // (row>>1)&3 == (lane>>3)&3
    const char* sB0h = (const char*)(Bh + (size_t)(bn + br0) * K) + bscb;
    const char* sB1h = (const char*)(Bh + (size_t)(bn + br0 + 16) * K) + bscb;
    const char* sB0l = (const char*)(Bl + (size_t)(bn + br0) * K) + bscb;
    const char* sB1l = (const char*)(Bl + (size_t)(bn + br0 + 16) * K) + bscb;
    // wave-uniform LDS dest bases (lane*16 added by HW)
    const int adst0 = (wid * 64) << 4;            // chunk region [wid*64 .. +64)
    const int adst1 = ((384 + wid * 64)) << 4;
    const int bdst0 = ((bw * 128) << 4);
    const int bdst1 = ((bw * 128 + 64) << 4);

#define GLL(srcp, dstoff)                                                               \
    __builtin_amdgcn_global_load_lds(                                                   \
        (const __attribute__((address_space(1))) void*)(srcp),                          \
        (__attribute__((address_space(3))) void*)((char*)&lds[buf][0] + (dstoff)), 16, 0, 0)

#define STAGE(bufv, k0)                                                                 \
    do {                                                                                \
        int buf = (bufv);                                                               \
        size_t kb2 = (size_t)(k0) * 2;                                                  \
        GLL(sA0h + kb2, adst0);                                                         \
        GLL(sA1h + kb2, adst1);                                                         \
        GLL(sA0l + kb2, 12288 + adst0);                                                 \
        GLL(sA1l + kb2, 12288 + adst1);                                                 \
        GLL(sB0h + kb2, 24576 + bdst0);                                                 \
        GLL(sB1h + kb2, 24576 + bdst1);                                                 \
        GLL(sB0l + kb2, 32768 + bdst0);                                                 \
        GLL(sB1l + kb2, 32768 + bdst1);                                                 \
    } while (0)

    STAGE(0, 0);

    const int NT = K / 32;
    const int hi = lane >> 5;        // k-half within 16-k step
    const int rl = lane & 31;
#pragma unroll
    for (int t = 0; t < NT; ++t) {
        int cur = t & 1;
        if (t + 1 < NT) {
            STAGE(cur ^ 1, (t + 1) * 32);
            asm volatile("s_waitcnt vmcnt(8)" ::: "memory");  // prev tile's 8 loads done
        } else {
            asm volatile("s_waitcnt vmcnt(0)" ::: "memory");
        }
        __builtin_amdgcn_s_barrier();
        asm volatile("" ::: "memory");

        const char* L = (const char*)&lds[cur][0];
#pragma unroll
        for (int kc = 0; kc < 2; ++kc) {
            int slot = kc * 2 + hi;
            bf16x8 a_h[2], a_l[2], b_h[2], b_l[2];
#pragma unroll
            for (int i = 0; i < 2; ++i) {
                int ra = wm + i * 32 + rl;
                int off = ra * 64 + ((slot ^ ((ra >> 1) & 3)) << 4);
                a_h[i] = *(const bf16x8*)(L + off);
                a_l[i] = *(const bf16x8*)(L + 12288 + off);
            }
#pragma unroll
            for (int j = 0; j < 2; ++j) {
                int rb = wn + j * 32 + rl;
                int off = rb * 64 + ((slot ^ ((rb >> 1) & 3)) << 4);
                b_h[j] = *(const bf16x8*)(L + 24576 + off);
                b_l[j] = *(const bf16x8*)(L + 32768 + off);
            }
#pragma unroll
            for (int i = 0; i < 2; ++i)
#pragma unroll
                for (int j = 0; j < 2; ++j) {
                    acc[i][j] = __builtin_amdgcn_mfma_f32_32x32x16_bf16(a_h[i], b_h[j], acc[i][j], 0, 0, 0);
                    acc[i][j] = __builtin_amdgcn_mfma_f32_32x32x16_bf16(a_l[i], b_h[j], acc[i][j], 0, 0, 0);
                    acc[i][j] = __builtin_amdgcn_mfma_f32_32x32x16_bf16(a_h[i], b_l[j], acc[i][j], 0, 0, 0);
                }
        }
        asm volatile("" ::: "memory");
        __builtin_amdgcn_s_barrier();
    }
#undef STAGE
#undef GLL

    // epilogue: 32x32 C/D layout col=lane&31, row=(reg&3)+8*(reg>>2)+4*(lane>>5) (m74/m101)
#pragma unroll
    for (int j = 0; j < 2; ++j) {
        int gc = bn + wn + j * 32 + rl;
        float bv = bias[gc];
#pragma unroll
        for (int i = 0; i < 2; ++i) {
#pragma unroll
            for (int reg = 0; reg < 16; ++reg) {
                int row = (reg & 3) + 8 * (reg >> 2) + 4 * hi;
                int gr = bm + wm + i * 32 + row;
                if (gr < M) {
                    float v = acc[i][j][reg] + bv;
                    if (RELU) v = fmaxf(v, 0.f);
                    if (OUT_BF16)
                        ((u16*)Cout)[(size_t)gr * N + gc] = f2bf(v);
                    else
                        ((float*)Cout)[(size_t)gr * N + gc] = v;
                }
            }
        }
    }
}

// ---------------------------------------------------------------- launch
extern "C" void kernel_launch(void* const* d_in, const int* in_sizes, int n_in,
                              void* d_out, int out_size, void* d_ws, size_t ws_size,
                              hipStream_t stream) {
    const float* x  = (const float*)d_in[0];
    const int*   ei = (const int*)d_in[1];
    const float* W1 = (const float*)d_in[2];
    const float* b1 = (const float*)d_in[3];
    const float* W2 = (const float*)d_in[4];
    const float* b2 = (const float*)d_in[5];
    const int* src = ei;
    const int* dst = ei + N_EDGES;

    char* ws = (char*)d_ws;
    size_t off = 0;
    auto alloc = [&](size_t bytes) {
        void* p = ws + off;
        off = (off + bytes + 255) & ~(size_t)255;
        return p;
    };
    int*   deg     = (int*)alloc(N_NODES * 4);  // reused as cursor
    int*   row_ptr = (int*)alloc((N_NODES + 1) * 4);
    float* dinv    = (float*)alloc(N_NODES * 4);
    int2*  epair   = (int2*)alloc((size_t)N_EDGES * 8);
    u16*   wt1_hi  = (u16*)alloc((size_t)IN_CH * HID_CH * 2);
    u16*   wt1_lo  = (u16*)alloc((size_t)IN_CH * HID_CH * 2);
    u16*   wt2_hi  = (u16*)alloc((size_t)HID_CH * HID_CH * 2);
    u16*   wt2_lo  = (u16*)alloc((size_t)HID_CH * HID_CH * 2);
    // overlay region: {xb, z1_hi, z1_lo} then {z2_hi, z2_lo}
    char*  R       = (char*)alloc((size_t)N_NODES * HID_CH * 2 * 2);  // 40.96 MB
    u16* xb    = (u16*)R;                                       // [N, 256]
    u16* z1_hi = (u16*)(R + (size_t)N_NODES * IN_CH * 2);       // [N, 256]
    u16* z1_lo = (u16*)(R + (size_t)N_NODES * IN_CH * 4);       // [N, 256]
    u16* z2_hi = (u16*)R;                                       // [N, 512] (over dead xb+z1_hi)
    u16* z2_lo = (u16*)(R + (size_t)N_NODES * HID_CH * 2);      // [N, 512] (over dead z1_lo)
    u16* h1    = (u16*)d_out;  // bf16 h1 scratch in d_out (dead before final GEMM writes)

    // CSR + dinv + epair
    hipMemsetAsync(deg, 0, N_NODES * 4, stream);
    count_deg_kernel<<<(N_EDGES + 255) / 256, 256, 0, stream>>>(dst, deg, N_EDGES);
    scan_kernel<<<1, 256, 0, stream>>>(deg, row_ptr, dinv, N_NODES);
    hipMemsetAsync(deg, 0, N_NODES * 4, stream);  // deg -> cursor
    scatter_edges_kernel<<<(N_EDGES + 255) / 256, 256, 0, stream>>>(src, dst, row_ptr, deg, dinv,
                                                                    epair, N_EDGES);

    // conversions
    f32_to_bf16_kernel<<<(N_NODES * IN_CH / 4 + 255) / 256, 256, 0, stream>>>(
        x, xb, N_NODES * IN_CH / 4);
    convert_w_kernel<<<96, 256, 0, stream>>>(W1, wt1_hi, wt1_lo, W2, wt2_hi, wt2_lo);

    const int NMT = (N_NODES + 191) / 192;  // 105 -> grid 420
    // layer 1: z1 = P @ xb ; h1 = relu(z1 @ W1 + b1)  (bf16 out)
    gather_agg_kernel<IN_CH><<<(N_NODES + 3) / 4, 256, 0, stream>>>(xb, epair, row_ptr, dinv,
                                                                    z1_hi, z1_lo, N_NODES);
    gemm_mfma_kernel<IN_CH, true, true><<<NMT * 4, 384, 0, stream>>>(
        z1_hi, z1_lo, wt1_hi, wt1_lo, b1, h1, N_NODES, HID_CH);

    // layer 2: z2 = P @ h1 ; out = z2 @ W2 + b2  (fp32 out)
    gather_agg_kernel<HID_CH><<<(N_NODES + 3) / 4, 256, 0, stream>>>(h1, epair, row_ptr, dinv,
                                                                     z2_hi, z2_lo, N_NODES);
    gemm_mfma_kernel<HID_CH, false, false><<<NMT * 4, 384, 0, stream>>>(
        z2_hi, z2_lo, wt2_hi, wt2_lo, b2, (float*)d_out, N_NODES, HID_CH);
}